// Round 1
// baseline (274.885 us; speedup 1.0000x reference)
//
#include <hip/hip_runtime.h>

// VolumeRenderer: N=65536 rays, L=192 samples.
//   delta[l] = depth[l+1]-depth[l] (last = 1e10)
//   alpha = 1 - exp(-relu(sigma)*delta)
//   w     = alpha * (1 - alpha + 1e-10)        (cumprod over size-1 axis = identity)
//   color = sum_l sigmoid(rgb[l]) * w[l]        -> (N,3)
//   depth_out = sum_l w[l]*depth[l]             -> (N,1)
// Memory-bound: 252 MB read / launch -> ~40 us floor at 6.3 TB/s.

constexpr int L = 192;

__device__ __forceinline__ float fast_sigmoid(float x) {
    return __builtin_amdgcn_rcpf(1.0f + __expf(-x));
}

__global__ __launch_bounds__(256) void volrender_kernel(
    const float* __restrict__ depth, const float* __restrict__ rgb,
    const float* __restrict__ sigma, float* __restrict__ out, int n_rays)
{
    const int lane = threadIdx.x & 63;
    const int ray  = (blockIdx.x << 2) + (threadIdx.x >> 6);  // 4 waves/block, wave = ray
    const long long base = (long long)ray * L;

    const float* dp = depth + base;
    const float* sp = sigma + base;
    const float* cp = rgb + base * 3;

    // lane handles samples lane, lane+64, lane+128 (coalesced across wave)
    float d0 = dp[lane], d1 = dp[lane + 64], d2 = dp[lane + 128];
    float s0 = sp[lane], s1 = sp[lane + 64], s2 = sp[lane + 128];

    // delta via neighbor shuffles (all lanes execute all shuffles uniformly)
    const int nxt = (lane + 1) & 63;
    float a0 = __shfl(d0, nxt);
    float a1 = __shfl(d1, nxt);
    float a2 = __shfl(d2, nxt);
    float b1 = __shfl(d1, 0);
    float b2 = __shfl(d2, 0);
    const bool lastlane = (lane == 63);
    float dl0 = (lastlane ? b1 : a0) - d0;
    float dl1 = (lastlane ? b2 : a1) - d1;
    float dl2 = lastlane ? 1e10f : (a2 - d2);   // sample 191: delta = 1e10

    float al0 = 1.0f - __expf(-fmaxf(s0, 0.0f) * dl0);
    float al1 = 1.0f - __expf(-fmaxf(s1, 0.0f) * dl1);
    float al2 = 1.0f - __expf(-fmaxf(s2, 0.0f) * dl2);
    float w0 = al0 * (1.0f - al0 + 1e-10f);
    float w1 = al1 * (1.0f - al1 + 1e-10f);
    float w2 = al2 * (1.0f - al2 + 1e-10f);

    // rgb: stride-3 scalar loads; the 3 channel loads per sample-chunk consume
    // the same cache lines -> no HBM over-fetch, L1 serves the reuse.
    const int i0 = 3 * lane;
    const int i1 = 3 * (lane + 64);
    const int i2 = 3 * (lane + 128);
    float cr = fast_sigmoid(cp[i0 + 0]) * w0
             + fast_sigmoid(cp[i1 + 0]) * w1
             + fast_sigmoid(cp[i2 + 0]) * w2;
    float cg = fast_sigmoid(cp[i0 + 1]) * w0
             + fast_sigmoid(cp[i1 + 1]) * w1
             + fast_sigmoid(cp[i2 + 1]) * w2;
    float cb = fast_sigmoid(cp[i0 + 2]) * w0
             + fast_sigmoid(cp[i1 + 2]) * w1
             + fast_sigmoid(cp[i2 + 2]) * w2;
    float dd = w0 * d0 + w1 * d1 + w2 * d2;

    // wave (64-lane) butterfly reduction
    #pragma unroll
    for (int off = 32; off > 0; off >>= 1) {
        cr += __shfl_xor(cr, off);
        cg += __shfl_xor(cg, off);
        cb += __shfl_xor(cb, off);
        dd += __shfl_xor(dd, off);
    }

    if (lane == 0) {
        out[ray * 3 + 0] = cr;
        out[ray * 3 + 1] = cg;
        out[ray * 3 + 2] = cb;
        out[(long long)n_rays * 3 + ray] = dd;  // depth output after color block
    }
}

extern "C" void kernel_launch(void* const* d_in, const int* in_sizes, int n_in,
                              void* d_out, int out_size, void* d_ws, size_t ws_size,
                              hipStream_t stream) {
    const float* depth = (const float*)d_in[0];
    const float* rgb   = (const float*)d_in[1];
    const float* sigma = (const float*)d_in[2];
    float* out = (float*)d_out;
    const int n_rays = in_sizes[0] / L;      // 65536
    const int blocks = n_rays / 4;           // 4 rays (waves) per 256-thread block
    volrender_kernel<<<blocks, 256, 0, stream>>>(depth, rgb, sigma, out, n_rays);
}